// Round 14
// baseline (605.591 us; speedup 1.0000x reference)
//
#include <hip/hip_runtime.h>

// Problem constants (from reference): H=256, N=100000, B=8, S=128 -> T=1024
#define T_ROWS 1024
#define H_DIM  256
#define N_COLS 100000
#define QF     127.0f

#define NB16   6250                // N/16 (exact)
#define NB3    782                 // ceil(N/128), last block 32 cols
#define TCH    4                   // t-chunks of 256
#define GRID3  (NB3 * TCH)         // 3128 = 8*391 -> bijective XCD swizzle

typedef __attribute__((ext_vector_type(4))) float f32x4;
typedef __attribute__((ext_vector_type(2))) float f32x2;
typedef __attribute__((ext_vector_type(8))) short short8;   // 8 bf16 (MFMA frag)
typedef __attribute__((ext_vector_type(4))) short short4v;  // 4 bf16 = 8B

// Exact f32 -> bf16 for integer-valued floats |q| <= 127: truncation is exact.
__device__ __forceinline__ short f32_to_bf16_exact(float f) {
    unsigned u = __builtin_bit_cast(unsigned, f);
    return (short)(u >> 16);
}

__device__ __forceinline__ float wave_absmax64(float v) {
#pragma unroll
    for (int off = 32; off > 0; off >>= 1)
        v = fmaxf(v, __shfl_xor(v, off, 64));
    return v;
}

// Raw LDS-only barrier: NO vmcnt drain (global stores stay in flight).
// lgkmcnt(0) + barrier gives cross-wave LDS visibility; dbuf makes buffer
// reuse race-free (reads of buf[i] drain at barrier i+1 before writes at i+2).
// Validated passing in R9/R10/R12/R13.
__device__ __forceinline__ void sync_lds() {
    asm volatile("s_waitcnt lgkmcnt(0)" ::: "memory");
    __builtin_amdgcn_s_barrier();
    __builtin_amdgcn_sched_barrier(0);
}

// ---------------- Kernel 1: quantize X -> FRAG-MAJOR bf16 x8F + absmax
// x8F layout: [tile(32)][kk(8)][mr(2)][lane(64)][j(8)] shorts.
// Element (t,k): tile=t>>5, mr=(t>>4)&1, lm=t&15, kk=k>>5, lg=(k&31)>>3, j=k&7,
// lane=lg*16+lm. A wave's frag load is then 64 lanes x 16B CONTIGUOUS.
__global__ __launch_bounds__(256) void quant_x(const float* __restrict__ X,
                                               short* __restrict__ x8F,
                                               float* __restrict__ sx) {
    const int w = threadIdx.x >> 6, l = threadIdx.x & 63;
    const int row = blockIdx.x * 4 + w;                 // t
    const float4 v = ((const float4*)X)[row * 64 + l];  // coalesced 16B/lane
    float amax = fmaxf(fmaxf(fabsf(v.x), fabsf(v.y)), fmaxf(fabsf(v.z), fabsf(v.w)));
    amax = wave_absmax64(amax);
    const float scale = (amax == 0.f) ? 1.f : amax;
    const float qs = QF / scale;
    short4v q;
    q.x = f32_to_bf16_exact(rintf(v.x * qs));
    q.y = f32_to_bf16_exact(rintf(v.y * qs));
    q.z = f32_to_bf16_exact(rintf(v.z * qs));
    q.w = f32_to_bf16_exact(rintf(v.w * qs));
    // k = 4l..4l+3 -> same (kk,lg), j = (4l)&7 in {0,4}: one contiguous 8B write
    const int tile = row >> 5, mr = (row >> 4) & 1, lm = row & 15;
    const int kk = l >> 3, lg = (l >> 1) & 3, j = (l & 1) * 4;
    const int lane = lg * 16 + lm;
    *(short4v*)(x8F + (((tile * 8 + kk) * 2 + mr) * 64 + lane) * 8 + j) = q;
    if (l == 0) sx[row] = amax;
}

// ---------------- Kernel 2: quantize W -> FRAG-MAJOR bf16 w8F + absmax
// w8F layout: [nb16(6250)][kk(8)][lane(64)][j(8)] shorts (8KB per 16-row block).
__global__ __launch_bounds__(256) void quant_w(const float* __restrict__ W,
                                               short* __restrict__ w8F,
                                               float* __restrict__ sw) {
    __shared__ short tile[16 * 256];
    const int tid = threadIdx.x;
    const int nb16 = blockIdx.x;                 // 0..6249
    const int r16 = tid >> 4, c16 = tid & 15;
    const int n = nb16 * 16 + r16;
    const float4* src = (const float4*)(W + (size_t)n * H_DIM + c16 * 16);
    float4 v[4];
    float amax = 0.f;
#pragma unroll
    for (int i = 0; i < 4; ++i) {
        v[i] = src[i];
        amax = fmaxf(amax, fmaxf(fmaxf(fabsf(v[i].x), fabsf(v[i].y)),
                                 fmaxf(fabsf(v[i].z), fabsf(v[i].w))));
    }
#pragma unroll
    for (int off = 8; off > 0; off >>= 1)
        amax = fmaxf(amax, __shfl_xor(amax, off, 64));
    const float scale = (amax == 0.f) ? 1.f : amax;
    const float qs = QF / scale;
    short qv[16];
#pragma unroll
    for (int i = 0; i < 4; ++i) {
        qv[i * 4 + 0] = f32_to_bf16_exact(rintf(v[i].x * qs));
        qv[i * 4 + 1] = f32_to_bf16_exact(rintf(v[i].y * qs));
        qv[i * 4 + 2] = f32_to_bf16_exact(rintf(v[i].z * qs));
        qv[i * 4 + 3] = f32_to_bf16_exact(rintf(v[i].w * qs));
    }
    *(short8*)&tile[r16 * 256 + c16 * 16]     = *(short8*)&qv[0];
    *(short8*)&tile[r16 * 256 + c16 * 16 + 8] = *(short8*)&qv[8];
    if (c16 == 0) sw[n] = amax;
    __syncthreads();
    const int kk = tid >> 5, i2 = tid & 31;
    const int L0 = 2 * i2, L1 = L0 + 1;
    short* dst = w8F + ((size_t)nb16 * 8 + kk) * 512 + i2 * 16;
    *(short8*)(dst)     = *(short8*)&tile[(L0 & 15) * 256 + kk * 32 + (L0 >> 4) * 8];
    *(short8*)(dst + 8) = *(short8*)&tile[(L1 & 15) * 256 + kk * 32 + (L1 >> 4) * 8];
}

// ---------------- Kernel 3: contiguous-VMEM GEMM (R13 base, verbatim)
// R14 single delta vs the PASSING 127.5µs R13 kernel: __launch_bounds__(256,5)
// -> 5 blocks/CU (LDS-capped max; VGPR=64 permits it). More resident blocks
// => store phases of different blocks interleave => more nt-write lines in
// flight per CU (the residual limiter theory).
__global__ __launch_bounds__(256, 5) void gemm_ctg(const short* __restrict__ x8F,
                                                   const float* __restrict__ sx,
                                                   const short* __restrict__ w8F,
                                                   const float* __restrict__ sw,
                                                   const float* __restrict__ bias,
                                                   float* __restrict__ out) {
    __shared__ float olds[2][32 * 128];   // 2 x 16KB

    // bijective XCD swizzle (3128 = 8*391); tc-inner -> w8 panel L2 reuse
    const int bid = blockIdx.x;
    const int s = (bid & 7) * (GRID3 / 8) + (bid >> 3);
    const int nb = s >> 2;                 // 0..781
    const int tc = s & 3;                  // t-chunk of 256 rows
    const int w = threadIdx.x >> 6, l = threadIdx.x & 63;
    const int lg = l >> 4, lm = l & 15;
    const int tbase = tc * 256;
    const int nb16w = nb * 8 + w * 2;      // this wave's first 16-row n-block

    // B-frags: 16 x 1KB contiguous loads, persist in regs across all 8 iters
    short8 bfr[2][8];
#pragma unroll
    for (int nf = 0; nf < 2; ++nf) {
        const int nbc = (nb16w + nf < NB16) ? (nb16w + nf) : (NB16 - 1);
        const short* B = w8F + (size_t)nbc * 4096 + l * 8;
#pragma unroll
        for (int kk = 0; kk < 8; ++kk)
            bfr[nf][kk] = *(const short8*)(B + kk * 512);
    }

    // store-side per-lane constants: this lane stores cols colb, colb+1
    const int colb = nb * 128 + 2 * l;
    const bool okc = colb < N_COLS;        // N even -> float2 fully in/out
    const int colc = okc ? colb : 0;
    const f32x2 sw2 = *(const f32x2*)(sw + colc);
    const f32x2 b2  = *(const f32x2*)(bias + colc);
    const float invqq = 1.0f / (QF * QF);

    const int tile0 = tbase >> 5;
    short8 acur[8], anxt[8];
    // preload (ii=0, mr=0)
#pragma unroll
    for (int kk = 0; kk < 8; ++kk)
        acur[kk] = *(const short8*)(x8F + (size_t)((tile0 * 8 + kk) * 2 + 0) * 512 + l * 8);

#pragma unroll 1
    for (int ii = 0; ii < 8; ++ii) {
        const int tile = tile0 + ii;
        f32x4 acc[2][2];
#pragma unroll
        for (int mr = 0; mr < 2; ++mr)
#pragma unroll
            for (int nf = 0; nf < 2; ++nf) acc[mr][nf] = (f32x4){0.f, 0.f, 0.f, 0.f};

        // ---- mr = 0: prefetch mr=1 frags, then MFMA on acur
#pragma unroll
        for (int kk = 0; kk < 8; ++kk)
            anxt[kk] = *(const short8*)(x8F + (size_t)((tile * 8 + kk) * 2 + 1) * 512 + l * 8);
#pragma unroll
        for (int kk = 0; kk < 8; ++kk) {
            acc[0][0] = __builtin_amdgcn_mfma_f32_16x16x32_bf16(bfr[0][kk], acur[kk], acc[0][0], 0, 0, 0);
            acc[0][1] = __builtin_amdgcn_mfma_f32_16x16x32_bf16(bfr[1][kk], acur[kk], acc[0][1], 0, 0, 0);
        }

        // ---- mr = 1: prefetch next iter's mr=0 frags, then MFMA on anxt
        if (ii < 7) {
#pragma unroll
            for (int kk = 0; kk < 8; ++kk)
                acur[kk] = *(const short8*)(x8F + (size_t)(((tile + 1) * 8 + kk) * 2 + 0) * 512 + l * 8);
        }
#pragma unroll
        for (int kk = 0; kk < 8; ++kk) {
            acc[1][0] = __builtin_amdgcn_mfma_f32_16x16x32_bf16(bfr[0][kk], anxt[kk], acc[1][0], 0, 0, 0);
            acc[1][1] = __builtin_amdgcn_mfma_f32_16x16x32_bf16(bfr[1][kk], anxt[kk], acc[1][1], 0, 0, 0);
        }

        // raw acc -> LDS, XOR-swizzled cols (bank spread)
        // D[n][t]: t = mr*16 + lm, n = w*32 + nf*16 + lg*4 + r
        float* ob = olds[ii & 1];
#pragma unroll
        for (int mr = 0; mr < 2; ++mr) {
            const int trow = mr * 16 + lm;
#pragma unroll
            for (int nf = 0; nf < 2; ++nf) {
                const int c = (w * 32 + nf * 16 + lg * 4) ^ ((trow & 7) << 2);
                *(f32x4*)(ob + trow * 128 + c) = acc[mr][nf];
            }
        }
        sync_lds();   // lgkmcnt(0) + raw s_barrier — NO vmcnt drain

        // store phase: wave w stores rows w*8..w*8+7; per row one 512B
        // unit-stride segment (64 lanes x float2), dequant on read.
        // NONTEMPORAL full-line no-allocate writes (validated R13).
        const int t0 = tbase + ii * 32;
#pragma unroll
        for (int i = 0; i < 8; ++i) {
            const int row = w * 8 + i;
            const int t = t0 + row;
            const float s0 = sx[t] * invqq;                  // wave-uniform
            const f32x2 v = *(const f32x2*)(ob + row * 128 + ((2 * l) ^ ((row & 7) << 2)));
            if (okc) {
                f32x2 o;
                o[0] = v[0] * (s0 * sw2[0]) + b2[0];
                o[1] = v[1] * (s0 * sw2[1]) + b2[1];
                __builtin_nontemporal_store(o, (f32x2*)(out + (size_t)t * N_COLS + colb));
            }
        }
        // dbuf + next iter's sync_lds protect this buffer until reads land
    }
}

extern "C" void kernel_launch(void* const* d_in, const int* in_sizes, int n_in,
                              void* d_out, int out_size, void* d_ws, size_t ws_size,
                              hipStream_t stream) {
    const float* X    = (const float*)d_in[0];   // [8,128,256] f32
    const float* W    = (const float*)d_in[1];   // [100000,256] f32
    const float* bias = (const float*)d_in[2];   // [100000] f32
    float* out = (float*)d_out;                  // [1024,100000] f32

    // ws layout: x8F 512KB | sx 4KB | w8F 51.2MB | sw 400KB (fits)
    const size_t x8_bytes = (size_t)T_ROWS * H_DIM * 2;
    const size_t sx_bytes = (size_t)T_ROWS * 4;
    const size_t w8_bytes = (size_t)N_COLS * H_DIM * 2;

    short* x8F = (short*)d_ws;
    float* sx  = (float*)((char*)d_ws + x8_bytes);
    short* w8F = (short*)((char*)d_ws + x8_bytes + sx_bytes);
    float* sw  = (float*)((char*)d_ws + x8_bytes + sx_bytes + w8_bytes);

    quant_x<<<T_ROWS / 4, 256, 0, stream>>>(X, x8F, sx);
    quant_w<<<NB16, 256, 0, stream>>>(W, w8F, sw);
    gemm_ctg<<<GRID3, 256, 0, stream>>>(x8F, sx, w8F, sw, bias, out);
}

// Round 15
// 341.906 us; speedup vs baseline: 1.7712x; 1.7712x over previous
//
#include <hip/hip_runtime.h>

// Problem constants (from reference): H=256, N=100000, B=8, S=128 -> T=1024
#define T_ROWS 1024
#define H_DIM  256
#define N_COLS 100000
#define QF     127.0f

#define NB16   6250                // N/16 (exact)
#define NB3    782                 // ceil(N/128), last block 32 cols
#define TCH    4                   // t-chunks of 256
#define GRID3  (NB3 * TCH)         // 3128 = 8*391 -> bijective XCD swizzle

typedef __attribute__((ext_vector_type(4))) float f32x4;
typedef __attribute__((ext_vector_type(2))) float f32x2;
typedef __attribute__((ext_vector_type(8))) short short8;   // 8 bf16 (MFMA frag)
typedef __attribute__((ext_vector_type(4))) short short4v;  // 4 bf16 = 8B

// Exact f32 -> bf16 for integer-valued floats |q| <= 127: truncation is exact.
__device__ __forceinline__ short f32_to_bf16_exact(float f) {
    unsigned u = __builtin_bit_cast(unsigned, f);
    return (short)(u >> 16);
}

__device__ __forceinline__ float wave_absmax64(float v) {
#pragma unroll
    for (int off = 32; off > 0; off >>= 1)
        v = fmaxf(v, __shfl_xor(v, off, 64));
    return v;
}

// Raw LDS-only barrier: NO vmcnt drain (global stores stay in flight).
// lgkmcnt(0) + barrier gives cross-wave LDS visibility; dbuf makes buffer
// reuse race-free (reads of buf[i] drain at barrier i+1 before writes at i+2).
// Validated passing in R9/R10/R12/R13.
__device__ __forceinline__ void sync_lds() {
    asm volatile("s_waitcnt lgkmcnt(0)" ::: "memory");
    __builtin_amdgcn_s_barrier();
    __builtin_amdgcn_sched_barrier(0);
}

// ---------------- Kernel 1: quantize X -> FRAG-MAJOR bf16 x8F + absmax
// x8F layout: [tile(32)][kk(8)][mr(2)][lane(64)][j(8)] shorts.
// Element (t,k): tile=t>>5, mr=(t>>4)&1, lm=t&15, kk=k>>5, lg=(k&31)>>3, j=k&7,
// lane=lg*16+lm. A wave's frag load is then 64 lanes x 16B CONTIGUOUS.
__global__ __launch_bounds__(256) void quant_x(const float* __restrict__ X,
                                               short* __restrict__ x8F,
                                               float* __restrict__ sx) {
    const int w = threadIdx.x >> 6, l = threadIdx.x & 63;
    const int row = blockIdx.x * 4 + w;                 // t
    const float4 v = ((const float4*)X)[row * 64 + l];  // coalesced 16B/lane
    float amax = fmaxf(fmaxf(fabsf(v.x), fabsf(v.y)), fmaxf(fabsf(v.z), fabsf(v.w)));
    amax = wave_absmax64(amax);
    const float scale = (amax == 0.f) ? 1.f : amax;
    const float qs = QF / scale;
    short4v q;
    q.x = f32_to_bf16_exact(rintf(v.x * qs));
    q.y = f32_to_bf16_exact(rintf(v.y * qs));
    q.z = f32_to_bf16_exact(rintf(v.z * qs));
    q.w = f32_to_bf16_exact(rintf(v.w * qs));
    // k = 4l..4l+3 -> same (kk,lg), j = (4l)&7 in {0,4}: one contiguous 8B write
    const int tile = row >> 5, mr = (row >> 4) & 1, lm = row & 15;
    const int kk = l >> 3, lg = (l >> 1) & 3, j = (l & 1) * 4;
    const int lane = lg * 16 + lm;
    *(short4v*)(x8F + (((tile * 8 + kk) * 2 + mr) * 64 + lane) * 8 + j) = q;
    if (l == 0) sx[row] = amax;
}

// ---------------- Kernel 2: quantize W -> FRAG-MAJOR bf16 w8F + absmax
// w8F layout: [nb16(6250)][kk(8)][lane(64)][j(8)] shorts (8KB per 16-row block).
__global__ __launch_bounds__(256) void quant_w(const float* __restrict__ W,
                                               short* __restrict__ w8F,
                                               float* __restrict__ sw) {
    __shared__ short tile[16 * 256];
    const int tid = threadIdx.x;
    const int nb16 = blockIdx.x;                 // 0..6249
    const int r16 = tid >> 4, c16 = tid & 15;
    const int n = nb16 * 16 + r16;
    const float4* src = (const float4*)(W + (size_t)n * H_DIM + c16 * 16);
    float4 v[4];
    float amax = 0.f;
#pragma unroll
    for (int i = 0; i < 4; ++i) {
        v[i] = src[i];
        amax = fmaxf(amax, fmaxf(fmaxf(fabsf(v[i].x), fabsf(v[i].y)),
                                 fmaxf(fabsf(v[i].z), fabsf(v[i].w))));
    }
#pragma unroll
    for (int off = 8; off > 0; off >>= 1)
        amax = fmaxf(amax, __shfl_xor(amax, off, 64));
    const float scale = (amax == 0.f) ? 1.f : amax;
    const float qs = QF / scale;
    short qv[16];
#pragma unroll
    for (int i = 0; i < 4; ++i) {
        qv[i * 4 + 0] = f32_to_bf16_exact(rintf(v[i].x * qs));
        qv[i * 4 + 1] = f32_to_bf16_exact(rintf(v[i].y * qs));
        qv[i * 4 + 2] = f32_to_bf16_exact(rintf(v[i].z * qs));
        qv[i * 4 + 3] = f32_to_bf16_exact(rintf(v[i].w * qs));
    }
    *(short8*)&tile[r16 * 256 + c16 * 16]     = *(short8*)&qv[0];
    *(short8*)&tile[r16 * 256 + c16 * 16 + 8] = *(short8*)&qv[8];
    if (c16 == 0) sw[n] = amax;
    __syncthreads();
    const int kk = tid >> 5, i2 = tid & 31;
    const int L0 = 2 * i2, L1 = L0 + 1;
    short* dst = w8F + ((size_t)nb16 * 8 + kk) * 512 + i2 * 16;
    *(short8*)(dst)     = *(short8*)&tile[(L0 & 15) * 256 + kk * 32 + (L0 >> 4) * 8];
    *(short8*)(dst + 8) = *(short8*)&tile[(L1 & 15) * 256 + kk * 32 + (L1 >> 4) * 8];
}

// ---------------- Kernel 3: contiguous-VMEM GEMM (R13 base, verbatim)
// R15 single delta vs the PASSING 127.5µs R13 kernel: __launch_bounds__(256,4)
// -> 4 blocks/CU. VGPR budget 512/4 = 128 >= the kernel's ~64 working set, so
// no spill (R14's (256,5) forced 48 VGPR -> scratch spills -> 605µs).
// LDS 4 x 32KB = 128KB <= 160KB. Clean occupancy step 3 -> 4.
__global__ __launch_bounds__(256, 4) void gemm_ctg(const short* __restrict__ x8F,
                                                   const float* __restrict__ sx,
                                                   const short* __restrict__ w8F,
                                                   const float* __restrict__ sw,
                                                   const float* __restrict__ bias,
                                                   float* __restrict__ out) {
    __shared__ float olds[2][32 * 128];   // 2 x 16KB

    // bijective XCD swizzle (3128 = 8*391); tc-inner -> w8 panel L2 reuse
    const int bid = blockIdx.x;
    const int s = (bid & 7) * (GRID3 / 8) + (bid >> 3);
    const int nb = s >> 2;                 // 0..781
    const int tc = s & 3;                  // t-chunk of 256 rows
    const int w = threadIdx.x >> 6, l = threadIdx.x & 63;
    const int lg = l >> 4, lm = l & 15;
    const int tbase = tc * 256;
    const int nb16w = nb * 8 + w * 2;      // this wave's first 16-row n-block

    // B-frags: 16 x 1KB contiguous loads, persist in regs across all 8 iters
    short8 bfr[2][8];
#pragma unroll
    for (int nf = 0; nf < 2; ++nf) {
        const int nbc = (nb16w + nf < NB16) ? (nb16w + nf) : (NB16 - 1);
        const short* B = w8F + (size_t)nbc * 4096 + l * 8;
#pragma unroll
        for (int kk = 0; kk < 8; ++kk)
            bfr[nf][kk] = *(const short8*)(B + kk * 512);
    }

    // store-side per-lane constants: this lane stores cols colb, colb+1
    const int colb = nb * 128 + 2 * l;
    const bool okc = colb < N_COLS;        // N even -> float2 fully in/out
    const int colc = okc ? colb : 0;
    const f32x2 sw2 = *(const f32x2*)(sw + colc);
    const f32x2 b2  = *(const f32x2*)(bias + colc);
    const float invqq = 1.0f / (QF * QF);

    const int tile0 = tbase >> 5;
    short8 acur[8], anxt[8];
    // preload (ii=0, mr=0)
#pragma unroll
    for (int kk = 0; kk < 8; ++kk)
        acur[kk] = *(const short8*)(x8F + (size_t)((tile0 * 8 + kk) * 2 + 0) * 512 + l * 8);

#pragma unroll 1
    for (int ii = 0; ii < 8; ++ii) {
        const int tile = tile0 + ii;
        f32x4 acc[2][2];
#pragma unroll
        for (int mr = 0; mr < 2; ++mr)
#pragma unroll
            for (int nf = 0; nf < 2; ++nf) acc[mr][nf] = (f32x4){0.f, 0.f, 0.f, 0.f};

        // ---- mr = 0: prefetch mr=1 frags, then MFMA on acur
#pragma unroll
        for (int kk = 0; kk < 8; ++kk)
            anxt[kk] = *(const short8*)(x8F + (size_t)((tile * 8 + kk) * 2 + 1) * 512 + l * 8);
#pragma unroll
        for (int kk = 0; kk < 8; ++kk) {
            acc[0][0] = __builtin_amdgcn_mfma_f32_16x16x32_bf16(bfr[0][kk], acur[kk], acc[0][0], 0, 0, 0);
            acc[0][1] = __builtin_amdgcn_mfma_f32_16x16x32_bf16(bfr[1][kk], acur[kk], acc[0][1], 0, 0, 0);
        }

        // ---- mr = 1: prefetch next iter's mr=0 frags, then MFMA on anxt
        if (ii < 7) {
#pragma unroll
            for (int kk = 0; kk < 8; ++kk)
                acur[kk] = *(const short8*)(x8F + (size_t)(((tile + 1) * 8 + kk) * 2 + 0) * 512 + l * 8);
        }
#pragma unroll
        for (int kk = 0; kk < 8; ++kk) {
            acc[1][0] = __builtin_amdgcn_mfma_f32_16x16x32_bf16(bfr[0][kk], anxt[kk], acc[1][0], 0, 0, 0);
            acc[1][1] = __builtin_amdgcn_mfma_f32_16x16x32_bf16(bfr[1][kk], anxt[kk], acc[1][1], 0, 0, 0);
        }

        // raw acc -> LDS, XOR-swizzled cols (bank spread)
        // D[n][t]: t = mr*16 + lm, n = w*32 + nf*16 + lg*4 + r
        float* ob = olds[ii & 1];
#pragma unroll
        for (int mr = 0; mr < 2; ++mr) {
            const int trow = mr * 16 + lm;
#pragma unroll
            for (int nf = 0; nf < 2; ++nf) {
                const int c = (w * 32 + nf * 16 + lg * 4) ^ ((trow & 7) << 2);
                *(f32x4*)(ob + trow * 128 + c) = acc[mr][nf];
            }
        }
        sync_lds();   // lgkmcnt(0) + raw s_barrier — NO vmcnt drain

        // store phase: wave w stores rows w*8..w*8+7; per row one 512B
        // unit-stride segment (64 lanes x float2), dequant on read.
        // NONTEMPORAL full-line no-allocate writes (validated R13).
        const int t0 = tbase + ii * 32;
#pragma unroll
        for (int i = 0; i < 8; ++i) {
            const int row = w * 8 + i;
            const int t = t0 + row;
            const float s0 = sx[t] * invqq;                  // wave-uniform
            const f32x2 v = *(const f32x2*)(ob + row * 128 + ((2 * l) ^ ((row & 7) << 2)));
            if (okc) {
                f32x2 o;
                o[0] = v[0] * (s0 * sw2[0]) + b2[0];
                o[1] = v[1] * (s0 * sw2[1]) + b2[1];
                __builtin_nontemporal_store(o, (f32x2*)(out + (size_t)t * N_COLS + colb));
            }
        }
        // dbuf + next iter's sync_lds protect this buffer until reads land
    }
}

extern "C" void kernel_launch(void* const* d_in, const int* in_sizes, int n_in,
                              void* d_out, int out_size, void* d_ws, size_t ws_size,
                              hipStream_t stream) {
    const float* X    = (const float*)d_in[0];   // [8,128,256] f32
    const float* W    = (const float*)d_in[1];   // [100000,256] f32
    const float* bias = (const float*)d_in[2];   // [100000] f32
    float* out = (float*)d_out;                  // [1024,100000] f32

    // ws layout: x8F 512KB | sx 4KB | w8F 51.2MB | sw 400KB (fits)
    const size_t x8_bytes = (size_t)T_ROWS * H_DIM * 2;
    const size_t sx_bytes = (size_t)T_ROWS * 4;
    const size_t w8_bytes = (size_t)N_COLS * H_DIM * 2;

    short* x8F = (short*)d_ws;
    float* sx  = (float*)((char*)d_ws + x8_bytes);
    short* w8F = (short*)((char*)d_ws + x8_bytes + sx_bytes);
    float* sw  = (float*)((char*)d_ws + x8_bytes + sx_bytes + w8_bytes);

    quant_x<<<T_ROWS / 4, 256, 0, stream>>>(X, x8F, sx);
    quant_w<<<NB16, 256, 0, stream>>>(W, w8F, sw);
    gemm_ctg<<<GRID3, 256, 0, stream>>>(x8F, sx, w8F, sw, bias, out);
}

// Round 16
// 127.510 us; speedup vs baseline: 4.7493x; 2.6814x over previous
//
#include <hip/hip_runtime.h>

// Problem constants (from reference): H=256, N=100000, B=8, S=128 -> T=1024
#define T_ROWS 1024
#define H_DIM  256
#define N_COLS 100000
#define QF     127.0f

#define NB16   6250                // N/16 (exact)
#define NB3    782                 // ceil(N/128), last block 32 cols
#define TCH    4                   // t-chunks of 256
#define GRID3  (NB3 * TCH)         // 3128 = 8*391 -> bijective XCD swizzle

typedef __attribute__((ext_vector_type(4))) float f32x4;
typedef __attribute__((ext_vector_type(2))) float f32x2;
typedef __attribute__((ext_vector_type(8))) short short8;   // 8 bf16 (MFMA frag)
typedef __attribute__((ext_vector_type(4))) short short4v;  // 4 bf16 = 8B

// Exact f32 -> bf16 for integer-valued floats |q| <= 127: truncation is exact.
__device__ __forceinline__ short f32_to_bf16_exact(float f) {
    unsigned u = __builtin_bit_cast(unsigned, f);
    return (short)(u >> 16);
}

__device__ __forceinline__ float wave_absmax64(float v) {
#pragma unroll
    for (int off = 32; off > 0; off >>= 1)
        v = fmaxf(v, __shfl_xor(v, off, 64));
    return v;
}

// Raw LDS-only barrier: NO vmcnt drain (global stores stay in flight).
// lgkmcnt(0) + barrier gives cross-wave LDS visibility; dbuf makes buffer
// reuse race-free (reads of buf[i] drain at barrier i+1 before writes at i+2).
// Validated passing in R9/R10/R12/R13.
__device__ __forceinline__ void sync_lds() {
    asm volatile("s_waitcnt lgkmcnt(0)" ::: "memory");
    __builtin_amdgcn_s_barrier();
    __builtin_amdgcn_sched_barrier(0);
}

// ---------------- Kernel 1: quantize X -> FRAG-MAJOR bf16 x8F + absmax
// x8F layout: [tile(32)][kk(8)][mr(2)][lane(64)][j(8)] shorts.
// Element (t,k): tile=t>>5, mr=(t>>4)&1, lm=t&15, kk=k>>5, lg=(k&31)>>3, j=k&7,
// lane=lg*16+lm. A wave's frag load is then 64 lanes x 16B CONTIGUOUS.
__global__ __launch_bounds__(256) void quant_x(const float* __restrict__ X,
                                               short* __restrict__ x8F,
                                               float* __restrict__ sx) {
    const int w = threadIdx.x >> 6, l = threadIdx.x & 63;
    const int row = blockIdx.x * 4 + w;                 // t
    const float4 v = ((const float4*)X)[row * 64 + l];  // coalesced 16B/lane
    float amax = fmaxf(fmaxf(fabsf(v.x), fabsf(v.y)), fmaxf(fabsf(v.z), fabsf(v.w)));
    amax = wave_absmax64(amax);
    const float scale = (amax == 0.f) ? 1.f : amax;
    const float qs = QF / scale;
    short4v q;
    q.x = f32_to_bf16_exact(rintf(v.x * qs));
    q.y = f32_to_bf16_exact(rintf(v.y * qs));
    q.z = f32_to_bf16_exact(rintf(v.z * qs));
    q.w = f32_to_bf16_exact(rintf(v.w * qs));
    // k = 4l..4l+3 -> same (kk,lg), j = (4l)&7 in {0,4}: one contiguous 8B write
    const int tile = row >> 5, mr = (row >> 4) & 1, lm = row & 15;
    const int kk = l >> 3, lg = (l >> 1) & 3, j = (l & 1) * 4;
    const int lane = lg * 16 + lm;
    *(short4v*)(x8F + (((tile * 8 + kk) * 2 + mr) * 64 + lane) * 8 + j) = q;
    if (l == 0) sx[row] = amax;
}

// ---------------- Kernel 2: quantize W -> FRAG-MAJOR bf16 w8F + absmax
// w8F layout: [nb16(6250)][kk(8)][lane(64)][j(8)] shorts (8KB per 16-row block).
__global__ __launch_bounds__(256) void quant_w(const float* __restrict__ W,
                                               short* __restrict__ w8F,
                                               float* __restrict__ sw) {
    __shared__ short tile[16 * 256];
    const int tid = threadIdx.x;
    const int nb16 = blockIdx.x;                 // 0..6249
    const int r16 = tid >> 4, c16 = tid & 15;
    const int n = nb16 * 16 + r16;
    const float4* src = (const float4*)(W + (size_t)n * H_DIM + c16 * 16);
    float4 v[4];
    float amax = 0.f;
#pragma unroll
    for (int i = 0; i < 4; ++i) {
        v[i] = src[i];
        amax = fmaxf(amax, fmaxf(fmaxf(fabsf(v[i].x), fabsf(v[i].y)),
                                 fmaxf(fabsf(v[i].z), fabsf(v[i].w))));
    }
#pragma unroll
    for (int off = 8; off > 0; off >>= 1)
        amax = fmaxf(amax, __shfl_xor(amax, off, 64));
    const float scale = (amax == 0.f) ? 1.f : amax;
    const float qs = QF / scale;
    short qv[16];
#pragma unroll
    for (int i = 0; i < 4; ++i) {
        qv[i * 4 + 0] = f32_to_bf16_exact(rintf(v[i].x * qs));
        qv[i * 4 + 1] = f32_to_bf16_exact(rintf(v[i].y * qs));
        qv[i * 4 + 2] = f32_to_bf16_exact(rintf(v[i].z * qs));
        qv[i * 4 + 3] = f32_to_bf16_exact(rintf(v[i].w * qs));
    }
    *(short8*)&tile[r16 * 256 + c16 * 16]     = *(short8*)&qv[0];
    *(short8*)&tile[r16 * 256 + c16 * 16 + 8] = *(short8*)&qv[8];
    if (c16 == 0) sw[n] = amax;
    __syncthreads();
    const int kk = tid >> 5, i2 = tid & 31;
    const int L0 = 2 * i2, L1 = L0 + 1;
    short* dst = w8F + ((size_t)nb16 * 8 + kk) * 512 + i2 * 16;
    *(short8*)(dst)     = *(short8*)&tile[(L0 & 15) * 256 + kk * 32 + (L0 >> 4) * 8];
    *(short8*)(dst + 8) = *(short8*)&tile[(L1 & 15) * 256 + kk * 32 + (L1 >> 4) * 8];
}

// ---------------- Kernel 3: contiguous-VMEM GEMM (R13 configuration, final)
// Proven optimum of this structure (127.5µs total): 3 blocks/CU keeps the
// shared 512KB x8F panel L2/L3-resident (4 blocks/CU thrashed it, R15;
// 5 forced spills, R14); per-inst unit-stride frag loads (R7); lgkm-only
// barrier, no vmcnt drain (R9); NONTEMPORAL full-line output stores (R13).
__global__ __launch_bounds__(256, 3) void gemm_ctg(const short* __restrict__ x8F,
                                                   const float* __restrict__ sx,
                                                   const short* __restrict__ w8F,
                                                   const float* __restrict__ sw,
                                                   const float* __restrict__ bias,
                                                   float* __restrict__ out) {
    __shared__ float olds[2][32 * 128];   // 2 x 16KB

    // bijective XCD swizzle (3128 = 8*391); tc-inner -> w8 panel L2 reuse
    const int bid = blockIdx.x;
    const int s = (bid & 7) * (GRID3 / 8) + (bid >> 3);
    const int nb = s >> 2;                 // 0..781
    const int tc = s & 3;                  // t-chunk of 256 rows
    const int w = threadIdx.x >> 6, l = threadIdx.x & 63;
    const int lg = l >> 4, lm = l & 15;
    const int tbase = tc * 256;
    const int nb16w = nb * 8 + w * 2;      // this wave's first 16-row n-block

    // B-frags: 16 x 1KB contiguous loads, persist in regs across all 8 iters
    short8 bfr[2][8];
#pragma unroll
    for (int nf = 0; nf < 2; ++nf) {
        const int nbc = (nb16w + nf < NB16) ? (nb16w + nf) : (NB16 - 1);
        const short* B = w8F + (size_t)nbc * 4096 + l * 8;
#pragma unroll
        for (int kk = 0; kk < 8; ++kk)
            bfr[nf][kk] = *(const short8*)(B + kk * 512);
    }

    // store-side per-lane constants: this lane stores cols colb, colb+1
    const int colb = nb * 128 + 2 * l;
    const bool okc = colb < N_COLS;        // N even -> float2 fully in/out
    const int colc = okc ? colb : 0;
    const f32x2 sw2 = *(const f32x2*)(sw + colc);
    const f32x2 b2  = *(const f32x2*)(bias + colc);
    const float invqq = 1.0f / (QF * QF);

    const int tile0 = tbase >> 5;
    short8 acur[8], anxt[8];
    // preload (ii=0, mr=0)
#pragma unroll
    for (int kk = 0; kk < 8; ++kk)
        acur[kk] = *(const short8*)(x8F + (size_t)((tile0 * 8 + kk) * 2 + 0) * 512 + l * 8);

#pragma unroll 1
    for (int ii = 0; ii < 8; ++ii) {
        const int tile = tile0 + ii;
        f32x4 acc[2][2];
#pragma unroll
        for (int mr = 0; mr < 2; ++mr)
#pragma unroll
            for (int nf = 0; nf < 2; ++nf) acc[mr][nf] = (f32x4){0.f, 0.f, 0.f, 0.f};

        // ---- mr = 0: prefetch mr=1 frags, then MFMA on acur
#pragma unroll
        for (int kk = 0; kk < 8; ++kk)
            anxt[kk] = *(const short8*)(x8F + (size_t)((tile * 8 + kk) * 2 + 1) * 512 + l * 8);
#pragma unroll
        for (int kk = 0; kk < 8; ++kk) {
            acc[0][0] = __builtin_amdgcn_mfma_f32_16x16x32_bf16(bfr[0][kk], acur[kk], acc[0][0], 0, 0, 0);
            acc[0][1] = __builtin_amdgcn_mfma_f32_16x16x32_bf16(bfr[1][kk], acur[kk], acc[0][1], 0, 0, 0);
        }

        // ---- mr = 1: prefetch next iter's mr=0 frags, then MFMA on anxt
        if (ii < 7) {
#pragma unroll
            for (int kk = 0; kk < 8; ++kk)
                acur[kk] = *(const short8*)(x8F + (size_t)(((tile + 1) * 8 + kk) * 2 + 0) * 512 + l * 8);
        }
#pragma unroll
        for (int kk = 0; kk < 8; ++kk) {
            acc[1][0] = __builtin_amdgcn_mfma_f32_16x16x32_bf16(bfr[0][kk], anxt[kk], acc[1][0], 0, 0, 0);
            acc[1][1] = __builtin_amdgcn_mfma_f32_16x16x32_bf16(bfr[1][kk], anxt[kk], acc[1][1], 0, 0, 0);
        }

        // raw acc -> LDS, XOR-swizzled cols (bank spread)
        // D[n][t]: t = mr*16 + lm, n = w*32 + nf*16 + lg*4 + r
        float* ob = olds[ii & 1];
#pragma unroll
        for (int mr = 0; mr < 2; ++mr) {
            const int trow = mr * 16 + lm;
#pragma unroll
            for (int nf = 0; nf < 2; ++nf) {
                const int c = (w * 32 + nf * 16 + lg * 4) ^ ((trow & 7) << 2);
                *(f32x4*)(ob + trow * 128 + c) = acc[mr][nf];
            }
        }
        sync_lds();   // lgkmcnt(0) + raw s_barrier — NO vmcnt drain

        // store phase: wave w stores rows w*8..w*8+7; per row one 512B
        // unit-stride segment (64 lanes x float2), dequant on read.
        // NONTEMPORAL full-line no-allocate writes (validated R13).
        const int t0 = tbase + ii * 32;
#pragma unroll
        for (int i = 0; i < 8; ++i) {
            const int row = w * 8 + i;
            const int t = t0 + row;
            const float s0 = sx[t] * invqq;                  // wave-uniform
            const f32x2 v = *(const f32x2*)(ob + row * 128 + ((2 * l) ^ ((row & 7) << 2)));
            if (okc) {
                f32x2 o;
                o[0] = v[0] * (s0 * sw2[0]) + b2[0];
                o[1] = v[1] * (s0 * sw2[1]) + b2[1];
                __builtin_nontemporal_store(o, (f32x2*)(out + (size_t)t * N_COLS + colb));
            }
        }
        // dbuf + next iter's sync_lds protect this buffer until reads land
    }
}

extern "C" void kernel_launch(void* const* d_in, const int* in_sizes, int n_in,
                              void* d_out, int out_size, void* d_ws, size_t ws_size,
                              hipStream_t stream) {
    const float* X    = (const float*)d_in[0];   // [8,128,256] f32
    const float* W    = (const float*)d_in[1];   // [100000,256] f32
    const float* bias = (const float*)d_in[2];   // [100000] f32
    float* out = (float*)d_out;                  // [1024,100000] f32

    // ws layout: x8F 512KB | sx 4KB | w8F 51.2MB | sw 400KB (fits)
    const size_t x8_bytes = (size_t)T_ROWS * H_DIM * 2;
    const size_t sx_bytes = (size_t)T_ROWS * 4;
    const size_t w8_bytes = (size_t)N_COLS * H_DIM * 2;

    short* x8F = (short*)d_ws;
    float* sx  = (float*)((char*)d_ws + x8_bytes);
    short* w8F = (short*)((char*)d_ws + x8_bytes + sx_bytes);
    float* sw  = (float*)((char*)d_ws + x8_bytes + sx_bytes + w8_bytes);

    quant_x<<<T_ROWS / 4, 256, 0, stream>>>(X, x8F, sx);
    quant_w<<<NB16, 256, 0, stream>>>(W, w8F, sw);
    gemm_ctg<<<GRID3, 256, 0, stream>>>(x8F, sx, w8F, sw, bias, out);
}